// Round 8
// baseline (161.091 us; speedup 1.0000x reference)
//
#include <hip/hip_runtime.h>

// Problem constants: B=2, T=1024, C=1024, H=16, D=64, K=C=1024.
#define T_DIM 1024
#define C_DIM 1024
#define H_DIM 16
#define D_DIM 64
#define KD    1024

typedef short  short8  __attribute__((ext_vector_type(8)));
typedef short  short4v __attribute__((ext_vector_type(4)));
typedef float  f32x4   __attribute__((ext_vector_type(4)));

__device__ __forceinline__ float bf2f(short s) {
  return __uint_as_float(((unsigned)(unsigned short)s) << 16);
}
__device__ __forceinline__ short f2bf(float f) {
  unsigned u = __float_as_uint(f);
  u += 0x7fffu + ((u >> 16) & 1u);   // round-to-nearest-even
  return (short)(u >> 16);
}
__device__ __forceinline__ unsigned pk2(float lo, float hi) {
  return ((unsigned)(unsigned short)f2bf(lo)) | (((unsigned)(unsigned short)f2bf(hi)) << 16);
}

// Async global->LDS 16B (m97 pattern; validated R12). Dest = uniform base + lane*16.
__device__ __forceinline__ void gl2lds16(const short* g, short* l) {
  __builtin_amdgcn_global_load_lds(
      (const __attribute__((address_space(1))) unsigned int*)(const void*)g,
      (__attribute__((address_space(3))) unsigned int*)(void*)l,
      16, 0, 0);
}

// Legacy-path helpers (fallback only).
__device__ __forceinline__ short8 ldfrag(const void* p, size_t off, int isf32) {
  if (isf32) {
    const float* q = (const float*)p + off;
    f32x4 lo = *(const f32x4*)q;
    f32x4 hi = *(const f32x4*)(q + 4);
    short8 r;
#pragma unroll
    for (int j = 0; j < 4; ++j) { r[j] = f2bf(lo[j]); r[j + 4] = f2bf(hi[j]); }
    return r;
  }
  return *(const short8*)((const short*)p + off);
}
__device__ __forceinline__ float ldbias(const void* b, int i, int isf32) {
  return isf32 ? ((const float*)b)[i] : bf2f(((const short*)b)[i]);
}

// In-kernel dtype probe (validated R6-R12).
__device__ __forceinline__ int detect_f32_inblock(const unsigned* w, int lane) {
  int c = 0;
#pragma unroll
  for (int i = 0; i < 4; ++i) {
    unsigned e = (w[lane * 4 + i] >> 7) & 0xffu;
    c += (e >= 110u && e <= 135u) ? 1 : 0;
  }
#pragma unroll
  for (int off = 32; off; off >>= 1) c += __shfl_xor(c, off);
  return (c < 128) ? 1 : 0;
}

#define SZE  ((size_t)2 * T_DIM * C_DIM)   // 2,097,152 elements
#define QN   ((size_t)2097152)
#define WN   ((size_t)1048576)
#define BN   ((size_t)1024)
#define CVT_TOT (3 * QN + 2 * WN + 2 * BN) // 8,390,656 (divisible by 4)

// ---------------------------------------------------------------------------
// One-time bf16 conversion prepass (validated R9-R12).
// ---------------------------------------------------------------------------
__global__ __launch_bounds__(256) void cvt_k(const void* __restrict__ q,
                                             const void* __restrict__ k,
                                             const void* __restrict__ v,
                                             const void* __restrict__ wk,
                                             const void* __restrict__ wc,
                                             const void* __restrict__ bk,
                                             const void* __restrict__ bc,
                                             short* __restrict__ dst)
{
  const int lane = threadIdx.x & 63;
  const int f = detect_f32_inblock((const unsigned*)q, lane);

  const size_t idx = (size_t)blockIdx.x * 1024 + threadIdx.x * 4;
  if (idx >= CVT_TOT) return;
  const void* src;
  size_t loc;
  if      (idx <     QN)          { src = q;  loc = idx; }
  else if (idx < 2 * QN)          { src = k;  loc = idx - QN; }
  else if (idx < 3 * QN)          { src = v;  loc = idx - 2 * QN; }
  else if (idx < 3 * QN + WN)     { src = wk; loc = idx - 3 * QN; }
  else if (idx < 3 * QN + 2 * WN) { src = wc; loc = idx - 3 * QN - WN; }
  else if (idx < 3 * QN + 2 * WN + BN) { src = bk; loc = idx - 3 * QN - 2 * WN; }
  else                            { src = bc; loc = idx - 3 * QN - 2 * WN - BN; }

  short4v o;
  if (f) {
    f32x4 x = *(const f32x4*)((const float*)src + loc);
#pragma unroll
    for (int j = 0; j < 4; ++j) o[j] = f2bf(x[j]);
  } else {
    o = *(const short4v*)((const short*)src + loc);
  }
  *(short4v*)(dst + idx) = o;
}

// ---------------------------------------------------------------------------
// BK=64 XOR-swizzled async staging (R13-verified scheme, unchanged).
// ---------------------------------------------------------------------------
__device__ __forceinline__ void stage8x8(const short* gsrc, short* S, int R0,
                                         int lane, int koff) {
  const int rw = R0 + (lane >> 3);
  const int q  = (lane & 7) ^ (rw & 7);
  gl2lds16(gsrc + (size_t)rw * KD + koff + q * 8, &S[R0 * 64]);
}
__device__ __forceinline__ short8 fragread64(const short* S, int row, int chunk) {
  const int sl = (row << 3) + (chunk ^ (row & 7));
  return *(const short8*)&S[sl << 3];
}

// ---------------------------------------------------------------------------
// Async fused QKV GEMM (R17 config, frozen): 128x64, BK=64, dbuf, XCD remap.
// ---------------------------------------------------------------------------
__global__ __launch_bounds__(256) void gemm_qkv_a(const short* __restrict__ X0,
                                                  const short* __restrict__ X1,
                                                  const short* __restrict__ X2,
                                                  const short* __restrict__ Wv,
                                                  const short* __restrict__ Bv,
                                                  short* __restrict__ outv)
{
  const int tid  = threadIdx.x;
  const int lane = tid & 63;
  const int wave = tid >> 6;
  const int col16 = lane & 15;
  const int quad  = lane >> 4;

  // XCD-L2 ownership remap (bijective: 768 = 8 XCD x 6 m x 16 c)
  const int f   = blockIdx.x;
  const int xcd = f & 7;
  const int j   = f >> 3;                 // [0,96)
  const int mt  = xcd * 6 + (j % 6);      // [0,48)
  const int ct  = j / 6;                  // [0,16)
  const int m0 = mt * 128;
  const int c0 = ct * 64;

  const int src = m0 >> 11;               // 0=q 1=k 2=v
  const short* Xv = (src == 0) ? X0 : (src == 1) ? X1 : X2;
  const int arow = m0 & 2047;
  const bool isv = (src == 2);
  short* outb = outv + (size_t)src * SZE;

  __shared__ short As[2][128 * 64];       // 32 KB (double-buffered)
  __shared__ short Bs[2][64 * 64];        // 16 KB (double-buffered)

  const short* Xg = Xv + (size_t)arow * KD;
  const short* Wg = Wv + (size_t)c0 * KD;

  f32x4 acc[2][4] = {};                   // [i = m-sub (wave*32+i*16)][j = c-sub]

  // prologue: fill buffer 0
  stage8x8(Xg, As[0], wave * 32,      lane, 0);
  stage8x8(Xg, As[0], wave * 32 + 8,  lane, 0);
  stage8x8(Xg, As[0], wave * 32 + 16, lane, 0);
  stage8x8(Xg, As[0], wave * 32 + 24, lane, 0);
  stage8x8(Wg, Bs[0], wave * 16,      lane, 0);
  stage8x8(Wg, Bs[0], wave * 16 + 8,  lane, 0);
  __syncthreads();                        // drains vmcnt; buf0 ready

  int cur = 0;
  for (int k0 = 0; k0 < KD; k0 += 64) {
    // prefetch next K-tile into the other buffer (overlaps compute below)
    if (k0 + 64 < KD) {
      short* An = As[cur ^ 1];
      short* Bn = Bs[cur ^ 1];
      stage8x8(Xg, An, wave * 32,      lane, k0 + 64);
      stage8x8(Xg, An, wave * 32 + 8,  lane, k0 + 64);
      stage8x8(Xg, An, wave * 32 + 16, lane, k0 + 64);
      stage8x8(Xg, An, wave * 32 + 24, lane, k0 + 64);
      stage8x8(Wg, Bn, wave * 16,      lane, k0 + 64);
      stage8x8(Wg, Bn, wave * 16 + 8,  lane, k0 + 64);
    }

    const short* Ac = As[cur];
    const short* Bc = Bs[cur];
#pragma unroll
    for (int kk = 0; kk < 2; ++kk) {
      short8 fx[2], fw[4];
#pragma unroll
      for (int i = 0; i < 2; ++i)
        fx[i] = fragread64(Ac, wave * 32 + i * 16 + col16, kk * 4 + quad);
#pragma unroll
      for (int jj = 0; jj < 4; ++jj)
        fw[jj] = fragread64(Bc, jj * 16 + col16, kk * 4 + quad);

      if (isv) {
#pragma unroll
        for (int i = 0; i < 2; ++i)
#pragma unroll
          for (int jj = 0; jj < 4; ++jj)
            acc[i][jj] = __builtin_amdgcn_mfma_f32_16x16x32_bf16(fx[i], fw[jj], acc[i][jj], 0, 0, 0);
      } else {
#pragma unroll
        for (int i = 0; i < 2; ++i)
#pragma unroll
          for (int jj = 0; jj < 4; ++jj)
            acc[i][jj] = __builtin_amdgcn_mfma_f32_16x16x32_bf16(fw[jj], fx[i], acc[i][jj], 0, 0, 0);
      }
    }

    __syncthreads();   // vmcnt(0): prefetch landed; lgkm: reads done; all waves synced
    cur ^= 1;
  }

  if (isv) {
    // NORM: col=c(d), rows=m(t) -> vpt [b,h,d,t]   (verified R5+)
#pragma unroll
    for (int i = 0; i < 2; ++i) {
#pragma unroll
      for (int jj = 0; jj < 4; ++jj) {
        const int c  = c0 + jj * 16 + col16;
        const int t0 = arow + wave * 32 + i * 16 + quad * 4;
        const float bv = bf2f(Bv[c]);
        short4v pk;
#pragma unroll
        for (int r = 0; r < 4; ++r) pk[r] = f2bf(acc[i][jj][r] + bv);
        const int bb = t0 >> 10, t = t0 & 1023, h = c >> 6, d = c & 63;
        size_t off = (size_t)((bb * H_DIM + h) * D_DIM + d) * T_DIM + t;
        *(short4v*)(outb + off) = pk;
      }
    }
  } else {
    // TRANS: col=m, rows=c -> qp/kp [b,h,t,d]   (verified R5+)
#pragma unroll
    for (int i = 0; i < 2; ++i) {
#pragma unroll
      for (int jj = 0; jj < 4; ++jj) {
        const int m  = arow + wave * 32 + i * 16 + col16;
        const int cb = c0 + jj * 16 + quad * 4;
        short4v bv4 = *(const short4v*)(Bv + cb);
        short4v pk;
#pragma unroll
        for (int r = 0; r < 4; ++r) pk[r] = f2bf(acc[i][jj][r] + bf2f(bv4[r]));
        const int bb = m >> 10, t = m & 1023, h = cb >> 6, d = cb & 63;
        size_t off = ((size_t)(bb * H_DIM + h) << 16) + (size_t)t * D_DIM + d;
        *(short4v*)(outb + off) = pk;
      }
    }
  }
}

// ---------------------------------------------------------------------------
// Async final GEMM (R17 config, frozen): 64x64, BK=64, dbuf, XCD remap.
// ---------------------------------------------------------------------------
__global__ __launch_bounds__(256) void gemm_out_a(const short* __restrict__ Xb,
                                                  const short* __restrict__ Wv,
                                                  const short* __restrict__ Bv,
                                                  float* __restrict__ outv)
{
  const int tid  = threadIdx.x;
  const int lane = tid & 63;
  const int wave = tid >> 6;
  const int col16 = lane & 15;
  const int quad  = lane >> 4;
  const int wm = wave & 1;
  const int wn = wave >> 1;

  // XCD-L2 ownership remap (bijective: 512 = 8 XCD x 4 m x 16 c)
  const int f   = blockIdx.x;
  const int xcd = f & 7;
  const int j   = f >> 3;                 // [0,64)
  const int mt  = xcd * 4 + (j % 4);      // [0,32)
  const int ct  = j / 4;                  // [0,16)
  const int m0 = mt * 64;
  const int c0 = ct * 64;

  __shared__ short As[2][64 * 64];        // 16 KB
  __shared__ short Bs[2][64 * 64];        // 16 KB

  const short* Xg = Xb + (size_t)m0 * KD;
  const short* Wg = Wv + (size_t)c0 * KD;

  f32x4 acc[2][2] = {};

  stage8x8(Xg, As[0], wave * 16,     lane, 0);
  stage8x8(Xg, As[0], wave * 16 + 8, lane, 0);
  stage8x8(Wg, Bs[0], wave * 16,     lane, 0);
  stage8x8(Wg, Bs[0], wave * 16 + 8, lane, 0);
  __syncthreads();

  int cur = 0;
  for (int k0 = 0; k0 < KD; k0 += 64) {
    if (k0 + 64 < KD) {
      short* An = As[cur ^ 1];
      short* Bn = Bs[cur ^ 1];
      stage8x8(Xg, An, wave * 16,     lane, k0 + 64);
      stage8x8(Xg, An, wave * 16 + 8, lane, k0 + 64);
      stage8x8(Wg, Bn, wave * 16,     lane, k0 + 64);
      stage8x8(Wg, Bn, wave * 16 + 8, lane, k0 + 64);
    }

    const short* Ac = As[cur];
    const short* Bc = Bs[cur];
#pragma unroll
    for (int kk = 0; kk < 2; ++kk) {
      short8 fx[2], fw[2];
#pragma unroll
      for (int i = 0; i < 2; ++i)
        fx[i] = fragread64(Ac, wm * 32 + i * 16 + col16, kk * 4 + quad);
#pragma unroll
      for (int jj = 0; jj < 2; ++jj)
        fw[jj] = fragread64(Bc, wn * 32 + jj * 16 + col16, kk * 4 + quad);

#pragma unroll
      for (int i = 0; i < 2; ++i)
#pragma unroll
        for (int jj = 0; jj < 2; ++jj)
          acc[i][jj] = __builtin_amdgcn_mfma_f32_16x16x32_bf16(fw[jj], fx[i], acc[i][jj], 0, 0, 0);
    }

    __syncthreads();
    cur ^= 1;
  }

#pragma unroll
  for (int i = 0; i < 2; ++i) {
#pragma unroll
    for (int jj = 0; jj < 2; ++jj) {
      const int m  = m0 + wm * 32 + i * 16 + col16;
      const int cb = c0 + wn * 32 + jj * 16 + quad * 4;
      f32x4 pv;
#pragma unroll
      for (int r = 0; r < 4; ++r) pv[r] = acc[i][jj][r] + bf2f(Bv[cb + r]);
      *(f32x4*)(outv + (size_t)m * C_DIM + cb) = pv;
    }
  }
}

// ---------------------------------------------------------------------------
// Legacy LDS-staged GEMM (R6/R10-verified) — fallback when ws too small.
// ---------------------------------------------------------------------------
#define LDSP 40

template<int KIND>
__global__ __launch_bounds__(256) void gemm2_k(const void* __restrict__ X0,
                                               const void* __restrict__ X1,
                                               const void* __restrict__ X2,
                                               const void* __restrict__ Wv,
                                               const void* __restrict__ Bv,
                                               void* __restrict__ outv)
{
  const int tid  = threadIdx.x;
  const int lane = tid & 63;
  const int wave = tid >> 6;
  const int col16 = lane & 15;
  const int quad  = lane >> 4;
  const int wm = wave & 1;
  const int wn = wave >> 1;

  const int f  = detect_f32_inblock((const unsigned*)Wv, lane);
  const int wf = f;
  const int xf = (KIND == 1) ? f : 0;

  const int m0 = blockIdx.x * 64;
  const int c0 = blockIdx.y * 64;

  const void* Xv = X0;
  int arow = m0;
  bool isv = false;
  short* outb = (short*)outv;
  if (KIND == 1) {
    const int src = m0 >> 11;
    Xv = (src == 0) ? X0 : (src == 1) ? X1 : X2;
    arow = m0 & 2047;
    isv = (src == 2);
    outb = (short*)outv + (size_t)src * SZE;
  }

  __shared__ short As[64 * LDSP];
  __shared__ short Bs[64 * LDSP];

  const int srow = tid >> 2;
  const int sc8  = tid & 3;

  f32x4 acc[2][2] = {};

  for (int k0 = 0; k0 < KD; k0 += 32) {
    short8 va = ldfrag(Xv, (size_t)(arow + srow) * KD + k0 + sc8 * 8, xf);
    short8 vb = ldfrag(Wv, (size_t)(c0 + srow) * KD + k0 + sc8 * 8, wf);
    if (k0) __syncthreads();
    *(short8*)&As[srow * LDSP + sc8 * 8] = va;
    *(short8*)&Bs[srow * LDSP + sc8 * 8] = vb;
    __syncthreads();

    short8 fx[2], fw[2];
#pragma unroll
    for (int i = 0; i < 2; ++i)
      fx[i] = *(const short8*)&As[(wm * 32 + i * 16 + col16) * LDSP + quad * 8];
#pragma unroll
    for (int jj = 0; jj < 2; ++jj)
      fw[jj] = *(const short8*)&Bs[(wn * 32 + jj * 16 + col16) * LDSP + quad * 8];

    if (KIND == 1 && isv) {
#pragma unroll
      for (int i = 0; i < 2; ++i)
#pragma unroll
        for (int jj = 0; jj < 2; ++jj)
          acc[i][jj] = __builtin_amdgcn_mfma_f32_16x16x32_bf16(fx[i], fw[jj], acc[i][jj], 0, 0, 0);
    } else {
#pragma unroll
      for (int i = 0; i < 2; ++i)
#pragma unroll
        for (int jj = 0; jj < 2; ++jj)
          acc[i][jj] = __builtin_amdgcn_mfma_f32_16x16x32_bf16(fw[jj], fx[i], acc[i][jj], 0, 0, 0);
    }
  }

  if (KIND == 1 && isv) {
#pragma unroll
    for (int i = 0; i < 2; ++i) {
#pragma unroll
      for (int jj = 0; jj < 2; ++jj) {
        const int c  = c0 + wn * 32 + jj * 16 + col16;
        const int t0 = arow + wm * 32 + i * 16 + quad * 4;
        const float bv = ldbias(Bv, c, wf);
        short4v pk;
#pragma unroll
        for (int r = 0; r < 4; ++r) pk[r] = f2bf(acc[i][jj][r] + bv);
        const int bb = t0 >> 10, t = t0 & 1023, h = c >> 6, d = c & 63;
        size_t off = (size_t)((bb * H_DIM + h) * D_DIM + d) * T_DIM + t;
        *(short4v*)(outb + off) = pk;
      }
    }
  } else {
#pragma unroll
    for (int i = 0; i < 2; ++i) {
#pragma unroll
      for (int jj = 0; jj < 2; ++jj) {
        const int m  = arow + wm * 32 + i * 16 + col16;
        const int cb = c0 + wn * 32 + jj * 16 + quad * 4;
        if (KIND == 0) {
          f32x4 pv;
#pragma unroll
          for (int r = 0; r < 4; ++r) pv[r] = acc[i][jj][r] + ldbias(Bv, cb + r, wf);
          *(f32x4*)((float*)outv + (size_t)m * C_DIM + cb) = pv;
        } else {
          short4v pk;
#pragma unroll
          for (int r = 0; r < 4; ++r) pk[r] = f2bf(acc[i][jj][r] + ldbias(Bv, cb + r, wf));
          const int bb = m >> 10, t = m & 1023, h = cb >> 6, d = cb & 63;
          size_t off = ((size_t)(bb * H_DIM + h) << 16) + (size_t)t * D_DIM + d;
          *(short4v*)(outb + off) = pk;
        }
      }
    }
  }
}

// ---------------------------------------------------------------------------
// Causal attention (R20): latency-chain fixes targeting the measured profile
// (42.7us, MfmaUtil 3.7%, VALUBusy 21%, all pipes idle -> dependency-bound).
//  1. K(jt=0) software-pipelined across kt iterations (register rotation);
//     K(jt=1) + next-K issued at body top -> L2 latency hides under MFMA.
//  2. V loads issued before the shuffle phase (~150-300cy of bpermute covers
//     the V round trip).
//  3. Om epilogue re-linearized [tile][quad][col]: old layout was 8-way bank
//     conflict (SQ_LDS_BANK_CONFLICT 1.46M); new is 2-way (free, m136).
//  4. unroll 1 (explicit pipeline replaces unroll-2; caps VGPR <= 64 to keep
//     8 waves/SIMD).
// ---------------------------------------------------------------------------
__global__ __launch_bounds__(256) void attn_k3(const short* __restrict__ qp,
                                               const short* __restrict__ kp,
                                               const short* __restrict__ vpt,
                                               short* __restrict__ y)
{
  const int lane = threadIdx.x & 63;
  const int wave = threadIdx.x >> 6;
  const int col  = lane & 15;
  const int quad = lane >> 4;
  const int bh = blockIdx.x;                 // XCD = bh % 8 (heuristic)
  const int b = bh >> 4, h = bh & 15;
  const int qt = 63 - (int)blockIdx.y;       // heavy blocks first
  const int q0 = qt * 16;
  const int myq = q0 + col;

  const short* qph = qp  + (size_t)bh * (T_DIM * D_DIM);
  const short* kph = kp  + (size_t)bh * (T_DIM * D_DIM);
  const short* vph = vpt + (size_t)bh * (D_DIM * T_DIM);

  const int nkt  = (q0 + 47) >> 5;
  const int base = nkt >> 2, rem = nkt & 3;
  const int cnt   = base + (wave < rem ? 1 : 0);
  const int start = wave * base + (wave < rem ? wave : rem);

  short8 bQ[2];
#pragma unroll
  for (int kk = 0; kk < 2; ++kk)
    bQ[kk] = *(const short8*)(qph + (size_t)(q0 + col) * D_DIM + kk * 32 + quad * 8);

  f32x4 O[4] = {};
  float rs = 0.0f;

  const int slA = col + ((quad & 1) * 32);
  const int slB = slA + 16;

  // software pipeline: K(jt=0) fragments for the CURRENT tile live across
  // iterations. Preload for the first tile (harmless over-read if cnt==0:
  // stays inside the workspace, values unused).
  short8 cK0a, cK0b;
  {
    const short* p0 = kph + (size_t)(start * 32 + col) * D_DIM + quad * 8;
    cK0a = *(const short8*)(p0);
    cK0b = *(const short8*)(p0 + 32);
  }

#pragma unroll 1
  for (int kt = start; kt < start + cnt; ++kt) {
    const int kb = kt * 32;

    // --- issue all independent loads first ---
    // K(jt=1) for this tile
    const short* kb1 = kph + (size_t)(kb + 16 + col) * D_DIM + quad * 8;
    short8 aK1a = *(const short8*)(kb1);
    short8 aK1b = *(const short8*)(kb1 + 32);
    // K(jt=0) for the NEXT tile (last iteration over-reads into vpt region:
    // in-bounds of the workspace, values unused)
    const short* nb0 = kph + (size_t)(kb + 32 + col) * D_DIM + quad * 8;
    short8 nK0a = *(const short8*)(nb0);
    short8 nK0b = *(const short8*)(nb0 + 32);

    // --- QK^T: jt=0 operands already resident (prefetched last iteration) ---
    f32x4 st[2];
    {
      f32x4 s = {0.f, 0.f, 0.f, 0.f};
      __builtin_amdgcn_s_setprio(1);
      s = __builtin_amdgcn_mfma_f32_16x16x32_bf16(cK0a, bQ[0], s, 0, 0, 0);
      s = __builtin_amdgcn_mfma_f32_16x16x32_bf16(cK0b, bQ[1], s, 0, 0, 0);
      st[0] = s;
      f32x4 t = {0.f, 0.f, 0.f, 0.f};
      t = __builtin_amdgcn_mfma_f32_16x16x32_bf16(aK1a, bQ[0], t, 0, 0, 0);
      t = __builtin_amdgcn_mfma_f32_16x16x32_bf16(aK1b, bQ[1], t, 0, 0, 0);
      __builtin_amdgcn_s_setprio(0);
      st[1] = t;
    }

    // --- softmax (no-max, causal mask) ---
#pragma unroll
    for (int jt = 0; jt < 2; ++jt) {
#pragma unroll
      for (int r = 0; r < 4; ++r) {
        const int key = kb + jt * 16 + quad * 4 + r;
        float p = __expf(st[jt][r] * 0.125f);
        p = (key > myq) ? 0.0f : p;
        st[jt][r] = p;
        rs += p;
      }
    }

    // V loads issued BEFORE the shuffle phase: bpermute latency covers them.
    short8 aV[4];
#pragma unroll
    for (int dt = 0; dt < 4; ++dt)
      aV[dt] = *(const short8*)(vph + (size_t)(dt * 16 + col) * T_DIM + kb + quad * 8);

    // --- P redistribution (verified R11/R12 shuffle scheme) ---
    const int a0 = (int)pk2(st[0][0], st[0][1]);
    const int a1 = (int)pk2(st[0][2], st[0][3]);
    const int b0 = (int)pk2(st[1][0], st[1][1]);
    const int b1 = (int)pk2(st[1][2], st[1][3]);
    const int tA0 = __shfl(a0, slA, 64), tB0 = __shfl(b0, slA, 64);
    const int tA1 = __shfl(a1, slA, 64), tB1 = __shfl(b1, slA, 64);
    const int tA2 = __shfl(a0, slB, 64), tB2 = __shfl(b0, slB, 64);
    const int tA3 = __shfl(a1, slB, 64), tB3 = __shfl(b1, slB, 64);
    union { unsigned u[4]; short8 s8; } uu;
    uu.u[0] = (unsigned)((quad < 2) ? tA0 : tB0);
    uu.u[1] = (unsigned)((quad < 2) ? tA1 : tB1);
    uu.u[2] = (unsigned)((quad < 2) ? tA2 : tB2);
    uu.u[3] = (unsigned)((quad < 2) ? tA3 : tB3);
    const short8 bP32 = uu.s8;

    // --- PV ---
    __builtin_amdgcn_s_setprio(1);
#pragma unroll
    for (int dt = 0; dt < 4; ++dt)
      O[dt] = __builtin_amdgcn_mfma_f32_16x16x32_bf16(aV[dt], bP32, O[dt], 0, 0, 0);
    __builtin_amdgcn_s_setprio(0);

    // rotate the K(jt=0) pipeline
    cK0a = nK0a;
    cK0b = nK0b;
  }

  rs += __shfl_xor(rs, 16);
  rs += __shfl_xor(rs, 32);

  // Epilogue reduction. Layout [tile][quad][col*4] -> lanes cover all 32
  // banks at exactly 2-way (free), vs 8-way in the old col-major indexing.
  __shared__ float Om[4 * 4 * 16 * 16];
  __shared__ float Ll[4][16];

#pragma unroll
  for (int dt = 0; dt < 4; ++dt)
    *(f32x4*)&Om[((wave * 4 + dt) * 4 + quad) * 64 + col * 4] = O[dt];
  if (quad == 0) Ll[wave][col] = rs;
  __syncthreads();

  float L = Ll[0][col] + Ll[1][col] + Ll[2][col] + Ll[3][col];
  f32x4 oacc = {0.f, 0.f, 0.f, 0.f};
#pragma unroll
  for (int w = 0; w < 4; ++w) {
    f32x4 ov = *(const f32x4*)&Om[((w * 4 + wave) * 4 + quad) * 64 + col * 4];
#pragma unroll
    for (int r = 0; r < 4; ++r) oacc[r] += ov[r];
  }
  const float rl = 1.0f / L;
  const int t = q0 + col;
  const size_t ybase = ((size_t)(b * T_DIM + t)) * C_DIM + h * D_DIM + quad * 4;
  short4v pk;
#pragma unroll
  for (int r = 0; r < 4; ++r) pk[r] = f2bf(oacc[r] * rl);
  *(short4v*)(y + ybase + wave * 16) = pk;
}

// ---------------------------------------------------------------------------
extern "C" void kernel_launch(void* const* d_in, const int* in_sizes, int n_in,
                              void* d_out, int out_size, void* d_ws, size_t ws_size,
                              hipStream_t stream) {
  const void* q = d_in[0];
  const void* k = d_in[1];
  const void* v = d_in[2];
  int wi = (n_in >= 8 && in_sizes[4] == C_DIM * C_DIM) ? 4 : 3;
  const void* Wk = d_in[wi];
  const void* bk = d_in[wi + 1];
  const void* Wc = d_in[wi + 2];
  const void* bc = d_in[wi + 3];

  short* ws  = (short*)d_ws;
  short* qp  = ws;                 // [b,h,t,d] bf16
  short* kp  = ws + SZE;           // [b,h,t,d] bf16
  short* vpt = ws + 2 * SZE;       // [b,h,d,t] bf16
  short* y   = ws + 3 * SZE;       // [b,t,c]   bf16

  short* ext = ws + 4 * SZE;
  const size_t needed = (4 * SZE + CVT_TOT) * sizeof(short);  // ~33.6 MB
  const bool pre = (ws_size >= needed);

  dim3 blk(256);
  if (pre) {
    cvt_k<<<dim3((unsigned)((CVT_TOT + 1023) / 1024)), blk, 0, stream>>>(
        q, k, v, Wk, Wc, bk, bc, ext);
    const short* gq  = ext;
    const short* gk  = ext + QN;
    const short* gv  = ext + 2 * QN;
    const short* gwk = ext + 3 * QN;
    const short* gwc = ext + 3 * QN + WN;
    const short* gbk = ext + 3 * QN + 2 * WN;
    const short* gbc = ext + 3 * QN + 2 * WN + BN;

    gemm_qkv_a<<<dim3(768), blk, 0, stream>>>(gq, gk, gv, gwk, gbk, qp);
    attn_k3<<<dim3(32, 64), blk, 0, stream>>>(qp, kp, vpt, y);
    gemm_out_a<<<dim3(512), blk, 0, stream>>>(y, gwc, gbc, (float*)d_out);
  } else {
    gemm2_k<1><<<dim3(96, 16), blk, 0, stream>>>(q, k, v, Wk, bk, qp);
    attn_k3<<<dim3(32, 64), blk, 0, stream>>>(qp, kp, vpt, y);
    gemm2_k<0><<<dim3(32, 16), blk, 0, stream>>>(y, nullptr, nullptr, Wc, bc, d_out);
  }
}

// Round 9
// 156.646 us; speedup vs baseline: 1.0284x; 1.0284x over previous
//
#include <hip/hip_runtime.h>

// Problem constants: B=2, T=1024, C=1024, H=16, D=64, K=C=1024.
#define T_DIM 1024
#define C_DIM 1024
#define H_DIM 16
#define D_DIM 64
#define KD    1024

typedef short  short8  __attribute__((ext_vector_type(8)));
typedef short  short4v __attribute__((ext_vector_type(4)));
typedef float  f32x4   __attribute__((ext_vector_type(4)));

__device__ __forceinline__ float bf2f(short s) {
  return __uint_as_float(((unsigned)(unsigned short)s) << 16);
}
__device__ __forceinline__ short f2bf(float f) {
  unsigned u = __float_as_uint(f);
  u += 0x7fffu + ((u >> 16) & 1u);   // round-to-nearest-even
  return (short)(u >> 16);
}
__device__ __forceinline__ unsigned pk2(float lo, float hi) {
  return ((unsigned)(unsigned short)f2bf(lo)) | (((unsigned)(unsigned short)f2bf(hi)) << 16);
}

// Async global->LDS 16B (m97 pattern; validated R12). Dest = uniform base + lane*16.
__device__ __forceinline__ void gl2lds16(const short* g, short* l) {
  __builtin_amdgcn_global_load_lds(
      (const __attribute__((address_space(1))) unsigned int*)(const void*)g,
      (__attribute__((address_space(3))) unsigned int*)(void*)l,
      16, 0, 0);
}

// Legacy-path helpers (fallback only).
__device__ __forceinline__ short8 ldfrag(const void* p, size_t off, int isf32) {
  if (isf32) {
    const float* q = (const float*)p + off;
    f32x4 lo = *(const f32x4*)q;
    f32x4 hi = *(const f32x4*)(q + 4);
    short8 r;
#pragma unroll
    for (int j = 0; j < 4; ++j) { r[j] = f2bf(lo[j]); r[j + 4] = f2bf(hi[j]); }
    return r;
  }
  return *(const short8*)((const short*)p + off);
}
__device__ __forceinline__ float ldbias(const void* b, int i, int isf32) {
  return isf32 ? ((const float*)b)[i] : bf2f(((const short*)b)[i]);
}

// In-kernel dtype probe (validated R6-R12).
__device__ __forceinline__ int detect_f32_inblock(const unsigned* w, int lane) {
  int c = 0;
#pragma unroll
  for (int i = 0; i < 4; ++i) {
    unsigned e = (w[lane * 4 + i] >> 7) & 0xffu;
    c += (e >= 110u && e <= 135u) ? 1 : 0;
  }
#pragma unroll
  for (int off = 32; off; off >>= 1) c += __shfl_xor(c, off);
  return (c < 128) ? 1 : 0;
}

#define SZE  ((size_t)2 * T_DIM * C_DIM)   // 2,097,152 elements
#define QN   ((size_t)2097152)
#define WN   ((size_t)1048576)
#define BN   ((size_t)1024)
#define CVT_TOT (3 * QN + 2 * WN + 2 * BN) // 8,390,656 (divisible by 4)

// ---------------------------------------------------------------------------
// One-time bf16 conversion prepass (validated R9-R12).
// ---------------------------------------------------------------------------
__global__ __launch_bounds__(256) void cvt_k(const void* __restrict__ q,
                                             const void* __restrict__ k,
                                             const void* __restrict__ v,
                                             const void* __restrict__ wk,
                                             const void* __restrict__ wc,
                                             const void* __restrict__ bk,
                                             const void* __restrict__ bc,
                                             short* __restrict__ dst)
{
  const int lane = threadIdx.x & 63;
  const int f = detect_f32_inblock((const unsigned*)q, lane);

  const size_t idx = (size_t)blockIdx.x * 1024 + threadIdx.x * 4;
  if (idx >= CVT_TOT) return;
  const void* src;
  size_t loc;
  if      (idx <     QN)          { src = q;  loc = idx; }
  else if (idx < 2 * QN)          { src = k;  loc = idx - QN; }
  else if (idx < 3 * QN)          { src = v;  loc = idx - 2 * QN; }
  else if (idx < 3 * QN + WN)     { src = wk; loc = idx - 3 * QN; }
  else if (idx < 3 * QN + 2 * WN) { src = wc; loc = idx - 3 * QN - WN; }
  else if (idx < 3 * QN + 2 * WN + BN) { src = bk; loc = idx - 3 * QN - 2 * WN; }
  else                            { src = bc; loc = idx - 3 * QN - 2 * WN - BN; }

  short4v o;
  if (f) {
    f32x4 x = *(const f32x4*)((const float*)src + loc);
#pragma unroll
    for (int j = 0; j < 4; ++j) o[j] = f2bf(x[j]);
  } else {
    o = *(const short4v*)((const short*)src + loc);
  }
  *(short4v*)(dst + idx) = o;
}

// ---------------------------------------------------------------------------
// BK=64 XOR-swizzled async staging (R13-verified scheme, unchanged).
// ---------------------------------------------------------------------------
__device__ __forceinline__ void stage8x8(const short* gsrc, short* S, int R0,
                                         int lane, int koff) {
  const int rw = R0 + (lane >> 3);
  const int q  = (lane & 7) ^ (rw & 7);
  gl2lds16(gsrc + (size_t)rw * KD + koff + q * 8, &S[R0 * 64]);
}
__device__ __forceinline__ short8 fragread64(const short* S, int row, int chunk) {
  const int sl = (row << 3) + (chunk ^ (row & 7));
  return *(const short8*)&S[sl << 3];
}

// ---------------------------------------------------------------------------
// Async fused QKV GEMM (R17 config, frozen): 128x64, BK=64, dbuf, XCD remap.
// ---------------------------------------------------------------------------
__global__ __launch_bounds__(256) void gemm_qkv_a(const short* __restrict__ X0,
                                                  const short* __restrict__ X1,
                                                  const short* __restrict__ X2,
                                                  const short* __restrict__ Wv,
                                                  const short* __restrict__ Bv,
                                                  short* __restrict__ outv)
{
  const int tid  = threadIdx.x;
  const int lane = tid & 63;
  const int wave = tid >> 6;
  const int col16 = lane & 15;
  const int quad  = lane >> 4;

  // XCD-L2 ownership remap (bijective: 768 = 8 XCD x 6 m x 16 c)
  const int f   = blockIdx.x;
  const int xcd = f & 7;
  const int j   = f >> 3;                 // [0,96)
  const int mt  = xcd * 6 + (j % 6);      // [0,48)
  const int ct  = j / 6;                  // [0,16)
  const int m0 = mt * 128;
  const int c0 = ct * 64;

  const int src = m0 >> 11;               // 0=q 1=k 2=v
  const short* Xv = (src == 0) ? X0 : (src == 1) ? X1 : X2;
  const int arow = m0 & 2047;
  const bool isv = (src == 2);
  short* outb = outv + (size_t)src * SZE;

  __shared__ short As[2][128 * 64];       // 32 KB (double-buffered)
  __shared__ short Bs[2][64 * 64];        // 16 KB (double-buffered)

  const short* Xg = Xv + (size_t)arow * KD;
  const short* Wg = Wv + (size_t)c0 * KD;

  f32x4 acc[2][4] = {};                   // [i = m-sub (wave*32+i*16)][j = c-sub]

  // prologue: fill buffer 0
  stage8x8(Xg, As[0], wave * 32,      lane, 0);
  stage8x8(Xg, As[0], wave * 32 + 8,  lane, 0);
  stage8x8(Xg, As[0], wave * 32 + 16, lane, 0);
  stage8x8(Xg, As[0], wave * 32 + 24, lane, 0);
  stage8x8(Wg, Bs[0], wave * 16,      lane, 0);
  stage8x8(Wg, Bs[0], wave * 16 + 8,  lane, 0);
  __syncthreads();                        // drains vmcnt; buf0 ready

  int cur = 0;
  for (int k0 = 0; k0 < KD; k0 += 64) {
    // prefetch next K-tile into the other buffer (overlaps compute below)
    if (k0 + 64 < KD) {
      short* An = As[cur ^ 1];
      short* Bn = Bs[cur ^ 1];
      stage8x8(Xg, An, wave * 32,      lane, k0 + 64);
      stage8x8(Xg, An, wave * 32 + 8,  lane, k0 + 64);
      stage8x8(Xg, An, wave * 32 + 16, lane, k0 + 64);
      stage8x8(Xg, An, wave * 32 + 24, lane, k0 + 64);
      stage8x8(Wg, Bn, wave * 16,      lane, k0 + 64);
      stage8x8(Wg, Bn, wave * 16 + 8,  lane, k0 + 64);
    }

    const short* Ac = As[cur];
    const short* Bc = Bs[cur];
#pragma unroll
    for (int kk = 0; kk < 2; ++kk) {
      short8 fx[2], fw[4];
#pragma unroll
      for (int i = 0; i < 2; ++i)
        fx[i] = fragread64(Ac, wave * 32 + i * 16 + col16, kk * 4 + quad);
#pragma unroll
      for (int jj = 0; jj < 4; ++jj)
        fw[jj] = fragread64(Bc, jj * 16 + col16, kk * 4 + quad);

      if (isv) {
#pragma unroll
        for (int i = 0; i < 2; ++i)
#pragma unroll
          for (int jj = 0; jj < 4; ++jj)
            acc[i][jj] = __builtin_amdgcn_mfma_f32_16x16x32_bf16(fx[i], fw[jj], acc[i][jj], 0, 0, 0);
      } else {
#pragma unroll
        for (int i = 0; i < 2; ++i)
#pragma unroll
          for (int jj = 0; jj < 4; ++jj)
            acc[i][jj] = __builtin_amdgcn_mfma_f32_16x16x32_bf16(fw[jj], fx[i], acc[i][jj], 0, 0, 0);
      }
    }

    __syncthreads();   // vmcnt(0): prefetch landed; lgkm: reads done; all waves synced
    cur ^= 1;
  }

  if (isv) {
    // NORM: col=c(d), rows=m(t) -> vpt [b,h,d,t]   (verified R5+)
#pragma unroll
    for (int i = 0; i < 2; ++i) {
#pragma unroll
      for (int jj = 0; jj < 4; ++jj) {
        const int c  = c0 + jj * 16 + col16;
        const int t0 = arow + wave * 32 + i * 16 + quad * 4;
        const float bv = bf2f(Bv[c]);
        short4v pk;
#pragma unroll
        for (int r = 0; r < 4; ++r) pk[r] = f2bf(acc[i][jj][r] + bv);
        const int bb = t0 >> 10, t = t0 & 1023, h = c >> 6, d = c & 63;
        size_t off = (size_t)((bb * H_DIM + h) * D_DIM + d) * T_DIM + t;
        *(short4v*)(outb + off) = pk;
      }
    }
  } else {
    // TRANS: col=m, rows=c -> qp/kp [b,h,t,d]   (verified R5+)
#pragma unroll
    for (int i = 0; i < 2; ++i) {
#pragma unroll
      for (int jj = 0; jj < 4; ++jj) {
        const int m  = arow + wave * 32 + i * 16 + col16;
        const int cb = c0 + jj * 16 + quad * 4;
        short4v bv4 = *(const short4v*)(Bv + cb);
        short4v pk;
#pragma unroll
        for (int r = 0; r < 4; ++r) pk[r] = f2bf(acc[i][jj][r] + bf2f(bv4[r]));
        const int bb = m >> 10, t = m & 1023, h = cb >> 6, d = cb & 63;
        size_t off = ((size_t)(bb * H_DIM + h) << 16) + (size_t)t * D_DIM + d;
        *(short4v*)(outb + off) = pk;
      }
    }
  }
}

// ---------------------------------------------------------------------------
// Async final GEMM (R17 config, frozen): 64x64, BK=64, dbuf, XCD remap.
// ---------------------------------------------------------------------------
__global__ __launch_bounds__(256) void gemm_out_a(const short* __restrict__ Xb,
                                                  const short* __restrict__ Wv,
                                                  const short* __restrict__ Bv,
                                                  float* __restrict__ outv)
{
  const int tid  = threadIdx.x;
  const int lane = tid & 63;
  const int wave = tid >> 6;
  const int col16 = lane & 15;
  const int quad  = lane >> 4;
  const int wm = wave & 1;
  const int wn = wave >> 1;

  // XCD-L2 ownership remap (bijective: 512 = 8 XCD x 4 m x 16 c)
  const int f   = blockIdx.x;
  const int xcd = f & 7;
  const int j   = f >> 3;                 // [0,64)
  const int mt  = xcd * 4 + (j % 4);      // [0,32)
  const int ct  = j / 4;                  // [0,16)
  const int m0 = mt * 64;
  const int c0 = ct * 64;

  __shared__ short As[2][64 * 64];        // 16 KB
  __shared__ short Bs[2][64 * 64];        // 16 KB

  const short* Xg = Xb + (size_t)m0 * KD;
  const short* Wg = Wv + (size_t)c0 * KD;

  f32x4 acc[2][2] = {};

  stage8x8(Xg, As[0], wave * 16,     lane, 0);
  stage8x8(Xg, As[0], wave * 16 + 8, lane, 0);
  stage8x8(Wg, Bs[0], wave * 16,     lane, 0);
  stage8x8(Wg, Bs[0], wave * 16 + 8, lane, 0);
  __syncthreads();

  int cur = 0;
  for (int k0 = 0; k0 < KD; k0 += 64) {
    if (k0 + 64 < KD) {
      short* An = As[cur ^ 1];
      short* Bn = Bs[cur ^ 1];
      stage8x8(Xg, An, wave * 16,     lane, k0 + 64);
      stage8x8(Xg, An, wave * 16 + 8, lane, k0 + 64);
      stage8x8(Wg, Bn, wave * 16,     lane, k0 + 64);
      stage8x8(Wg, Bn, wave * 16 + 8, lane, k0 + 64);
    }

    const short* Ac = As[cur];
    const short* Bc = Bs[cur];
#pragma unroll
    for (int kk = 0; kk < 2; ++kk) {
      short8 fx[2], fw[2];
#pragma unroll
      for (int i = 0; i < 2; ++i)
        fx[i] = fragread64(Ac, wm * 32 + i * 16 + col16, kk * 4 + quad);
#pragma unroll
      for (int jj = 0; jj < 2; ++jj)
        fw[jj] = fragread64(Bc, wn * 32 + jj * 16 + col16, kk * 4 + quad);

#pragma unroll
      for (int i = 0; i < 2; ++i)
#pragma unroll
        for (int jj = 0; jj < 2; ++jj)
          acc[i][jj] = __builtin_amdgcn_mfma_f32_16x16x32_bf16(fw[jj], fx[i], acc[i][jj], 0, 0, 0);
    }

    __syncthreads();
    cur ^= 1;
  }

#pragma unroll
  for (int i = 0; i < 2; ++i) {
#pragma unroll
    for (int jj = 0; jj < 2; ++jj) {
      const int m  = m0 + wm * 32 + i * 16 + col16;
      const int cb = c0 + wn * 32 + jj * 16 + quad * 4;
      f32x4 pv;
#pragma unroll
      for (int r = 0; r < 4; ++r) pv[r] = acc[i][jj][r] + bf2f(Bv[cb + r]);
      *(f32x4*)(outv + (size_t)m * C_DIM + cb) = pv;
    }
  }
}

// ---------------------------------------------------------------------------
// Legacy LDS-staged GEMM (R6/R10-verified) — fallback when ws too small.
// ---------------------------------------------------------------------------
#define LDSP 40

template<int KIND>
__global__ __launch_bounds__(256) void gemm2_k(const void* __restrict__ X0,
                                               const void* __restrict__ X1,
                                               const void* __restrict__ X2,
                                               const void* __restrict__ Wv,
                                               const void* __restrict__ Bv,
                                               void* __restrict__ outv)
{
  const int tid  = threadIdx.x;
  const int lane = tid & 63;
  const int wave = tid >> 6;
  const int col16 = lane & 15;
  const int quad  = lane >> 4;
  const int wm = wave & 1;
  const int wn = wave >> 1;

  const int f  = detect_f32_inblock((const unsigned*)Wv, lane);
  const int wf = f;
  const int xf = (KIND == 1) ? f : 0;

  const int m0 = blockIdx.x * 64;
  const int c0 = blockIdx.y * 64;

  const void* Xv = X0;
  int arow = m0;
  bool isv = false;
  short* outb = (short*)outv;
  if (KIND == 1) {
    const int src = m0 >> 11;
    Xv = (src == 0) ? X0 : (src == 1) ? X1 : X2;
    arow = m0 & 2047;
    isv = (src == 2);
    outb = (short*)outv + (size_t)src * SZE;
  }

  __shared__ short As[64 * LDSP];
  __shared__ short Bs[64 * LDSP];

  const int srow = tid >> 2;
  const int sc8  = tid & 3;

  f32x4 acc[2][2] = {};

  for (int k0 = 0; k0 < KD; k0 += 32) {
    short8 va = ldfrag(Xv, (size_t)(arow + srow) * KD + k0 + sc8 * 8, xf);
    short8 vb = ldfrag(Wv, (size_t)(c0 + srow) * KD + k0 + sc8 * 8, wf);
    if (k0) __syncthreads();
    *(short8*)&As[srow * LDSP + sc8 * 8] = va;
    *(short8*)&Bs[srow * LDSP + sc8 * 8] = vb;
    __syncthreads();

    short8 fx[2], fw[2];
#pragma unroll
    for (int i = 0; i < 2; ++i)
      fx[i] = *(const short8*)&As[(wm * 32 + i * 16 + col16) * LDSP + quad * 8];
#pragma unroll
    for (int jj = 0; jj < 2; ++jj)
      fw[jj] = *(const short8*)&Bs[(wn * 32 + jj * 16 + col16) * LDSP + quad * 8];

    if (KIND == 1 && isv) {
#pragma unroll
      for (int i = 0; i < 2; ++i)
#pragma unroll
        for (int jj = 0; jj < 2; ++jj)
          acc[i][jj] = __builtin_amdgcn_mfma_f32_16x16x32_bf16(fx[i], fw[jj], acc[i][jj], 0, 0, 0);
    } else {
#pragma unroll
      for (int i = 0; i < 2; ++i)
#pragma unroll
        for (int jj = 0; jj < 2; ++jj)
          acc[i][jj] = __builtin_amdgcn_mfma_f32_16x16x32_bf16(fw[jj], fx[i], acc[i][jj], 0, 0, 0);
    }
  }

  if (KIND == 1 && isv) {
#pragma unroll
    for (int i = 0; i < 2; ++i) {
#pragma unroll
      for (int jj = 0; jj < 2; ++jj) {
        const int c  = c0 + wn * 32 + jj * 16 + col16;
        const int t0 = arow + wm * 32 + i * 16 + quad * 4;
        const float bv = ldbias(Bv, c, wf);
        short4v pk;
#pragma unroll
        for (int r = 0; r < 4; ++r) pk[r] = f2bf(acc[i][jj][r] + bv);
        const int bb = t0 >> 10, t = t0 & 1023, h = c >> 6, d = c & 63;
        size_t off = (size_t)((bb * H_DIM + h) * D_DIM + d) * T_DIM + t;
        *(short4v*)(outb + off) = pk;
      }
    }
  } else {
#pragma unroll
    for (int i = 0; i < 2; ++i) {
#pragma unroll
      for (int jj = 0; jj < 2; ++jj) {
        const int m  = arow + wm * 32 + i * 16 + col16;
        const int cb = c0 + wn * 32 + jj * 16 + quad * 4;
        if (KIND == 0) {
          f32x4 pv;
#pragma unroll
          for (int r = 0; r < 4; ++r) pv[r] = acc[i][jj][r] + ldbias(Bv, cb + r, wf);
          *(f32x4*)((float*)outv + (size_t)m * C_DIM + cb) = pv;
        } else {
          short4v pk;
#pragma unroll
          for (int r = 0; r < 4; ++r) pk[r] = f2bf(acc[i][jj][r] + ldbias(Bv, cb + r, wf));
          const int bb = m >> 10, t = m & 1023, h = cb >> 6, d = cb & 63;
          size_t off = ((size_t)(bb * H_DIM + h) << 16) + (size_t)t * D_DIM + d;
          *(short4v*)(outb + off) = pk;
        }
      }
    }
  }
}

// ---------------------------------------------------------------------------
// Causal attention (R21): ONE WAVE OWNS ONE Q-TILE end-to-end.
//  The 4-wave key-split existed only to share a q-tile and forced a
//  barrier + 16KB LDS Om-reduction epilogue per block (2048 blocks). Now:
//  - zero LDS, zero barriers: denominator completes with the existing
//    2x shfl_xor (wave owns ALL keys of its q-tile); O written directly.
//  - per-tile body identical to R20 (K register pipeline, V-hoist, setprio,
//    verified shuffle scheme) but chains now span ~17 sequential tiles.
//  - balanced wave->qt map: block g waves take {2g, 63-2g, 2g+1, 62-2g}
//    -> every block ~69 key-tiles (bijective over qt in [0,64)).
//  Grid (32,16) = 512 blocks = 2/CU; XCD-pin preserved (flat%8 = bh%8).
//  K-prefetch over-read on last tile lands in vpt region (in-workspace,
//  values unused).
// ---------------------------------------------------------------------------
__global__ __launch_bounds__(256) void attn_k4(const short* __restrict__ qp,
                                               const short* __restrict__ kp,
                                               const short* __restrict__ vpt,
                                               short* __restrict__ y)
{
  const int lane = threadIdx.x & 63;
  const int wave = threadIdx.x >> 6;
  const int col  = lane & 15;
  const int quad = lane >> 4;
  const int bh = blockIdx.x;                 // XCD = bh % 8 (heuristic)
  const int b = bh >> 4, h = bh & 15;
  const int g = (int)blockIdx.y;             // [0,16)
  const int qt = (wave == 0) ? 2 * g
               : (wave == 1) ? 63 - 2 * g
               : (wave == 2) ? 2 * g + 1
               :               62 - 2 * g;
  const int q0 = qt * 16;
  const int myq = q0 + col;

  const short* qph = qp  + (size_t)bh * (T_DIM * D_DIM);
  const short* kph = kp  + (size_t)bh * (T_DIM * D_DIM);
  const short* vph = vpt + (size_t)bh * (D_DIM * T_DIM);

  const int cnt = (q0 + 47) >> 5;            // key tiles [0, cnt), cnt >= 1

  short8 bQ[2];
#pragma unroll
  for (int kk = 0; kk < 2; ++kk)
    bQ[kk] = *(const short8*)(qph + (size_t)(q0 + col) * D_DIM + kk * 32 + quad * 8);

  f32x4 O[4] = {};
  float rs = 0.0f;

  const int slA = col + ((quad & 1) * 32);
  const int slB = slA + 16;

  // K(jt=0) software pipeline: preload tile 0.
  short8 cK0a, cK0b;
  {
    const short* p0 = kph + (size_t)(col) * D_DIM + quad * 8;
    cK0a = *(const short8*)(p0);
    cK0b = *(const short8*)(p0 + 32);
  }

#pragma unroll 1
  for (int kt = 0; kt < cnt; ++kt) {
    const int kb = kt * 32;

    // --- issue all independent loads first ---
    const short* kb1 = kph + (size_t)(kb + 16 + col) * D_DIM + quad * 8;
    short8 aK1a = *(const short8*)(kb1);
    short8 aK1b = *(const short8*)(kb1 + 32);
    // next-tile K(jt=0) (last iteration over-reads into vpt region: safe)
    const short* nb0 = kph + (size_t)(kb + 32 + col) * D_DIM + quad * 8;
    short8 nK0a = *(const short8*)(nb0);
    short8 nK0b = *(const short8*)(nb0 + 32);

    // --- QK^T (jt=0 operands resident from previous iteration) ---
    f32x4 st[2];
    {
      f32x4 s = {0.f, 0.f, 0.f, 0.f};
      __builtin_amdgcn_s_setprio(1);
      s = __builtin_amdgcn_mfma_f32_16x16x32_bf16(cK0a, bQ[0], s, 0, 0, 0);
      s = __builtin_amdgcn_mfma_f32_16x16x32_bf16(cK0b, bQ[1], s, 0, 0, 0);
      st[0] = s;
      f32x4 t = {0.f, 0.f, 0.f, 0.f};
      t = __builtin_amdgcn_mfma_f32_16x16x32_bf16(aK1a, bQ[0], t, 0, 0, 0);
      t = __builtin_amdgcn_mfma_f32_16x16x32_bf16(aK1b, bQ[1], t, 0, 0, 0);
      __builtin_amdgcn_s_setprio(0);
      st[1] = t;
    }

    // --- softmax (no-max, causal mask) ---
#pragma unroll
    for (int jt = 0; jt < 2; ++jt) {
#pragma unroll
      for (int r = 0; r < 4; ++r) {
        const int key = kb + jt * 16 + quad * 4 + r;
        float p = __expf(st[jt][r] * 0.125f);
        p = (key > myq) ? 0.0f : p;
        st[jt][r] = p;
        rs += p;
      }
    }

    // V loads before the shuffle phase (bpermute latency covers them).
    short8 aV[4];
#pragma unroll
    for (int dt = 0; dt < 4; ++dt)
      aV[dt] = *(const short8*)(vph + (size_t)(dt * 16 + col) * T_DIM + kb + quad * 8);

    // --- P redistribution (verified R11/R12 shuffle scheme) ---
    const int a0 = (int)pk2(st[0][0], st[0][1]);
    const int a1 = (int)pk2(st[0][2], st[0][3]);
    const int b0 = (int)pk2(st[1][0], st[1][1]);
    const int b1 = (int)pk2(st[1][2], st[1][3]);
    const int tA0 = __shfl(a0, slA, 64), tB0 = __shfl(b0, slA, 64);
    const int tA1 = __shfl(a1, slA, 64), tB1 = __shfl(b1, slA, 64);
    const int tA2 = __shfl(a0, slB, 64), tB2 = __shfl(b0, slB, 64);
    const int tA3 = __shfl(a1, slB, 64), tB3 = __shfl(b1, slB, 64);
    union { unsigned u[4]; short8 s8; } uu;
    uu.u[0] = (unsigned)((quad < 2) ? tA0 : tB0);
    uu.u[1] = (unsigned)((quad < 2) ? tA1 : tB1);
    uu.u[2] = (unsigned)((quad < 2) ? tA2 : tB2);
    uu.u[3] = (unsigned)((quad < 2) ? tA3 : tB3);
    const short8 bP32 = uu.s8;

    // --- PV ---
    __builtin_amdgcn_s_setprio(1);
#pragma unroll
    for (int dt = 0; dt < 4; ++dt)
      O[dt] = __builtin_amdgcn_mfma_f32_16x16x32_bf16(aV[dt], bP32, O[dt], 0, 0, 0);
    __builtin_amdgcn_s_setprio(0);

    // rotate the K(jt=0) pipeline
    cK0a = nK0a;
    cK0b = nK0b;
  }

  // Complete softmax denominator: reduce across the 4 quads (wave owns all
  // keys of its q-tile, so this is the full sum).
  rs += __shfl_xor(rs, 16);
  rs += __shfl_xor(rs, 32);
  const float rl = 1.0f / rs;

  // Direct output write: lane(col,quad) holds d = dt*16 + quad*4 + r for
  // q-row t = q0 + col (verified C-layout, R5+).
  const int t = q0 + col;
  const size_t ybase = ((size_t)(b * T_DIM + t)) * C_DIM + h * D_DIM + quad * 4;
#pragma unroll
  for (int dt = 0; dt < 4; ++dt) {
    short4v pk;
#pragma unroll
    for (int r = 0; r < 4; ++r) pk[r] = f2bf(O[dt][r] * rl);
    *(short4v*)(y + ybase + dt * 16) = pk;
  }
}

// ---------------------------------------------------------------------------
extern "C" void kernel_launch(void* const* d_in, const int* in_sizes, int n_in,
                              void* d_out, int out_size, void* d_ws, size_t ws_size,
                              hipStream_t stream) {
  const void* q = d_in[0];
  const void* k = d_in[1];
  const void* v = d_in[2];
  int wi = (n_in >= 8 && in_sizes[4] == C_DIM * C_DIM) ? 4 : 3;
  const void* Wk = d_in[wi];
  const void* bk = d_in[wi + 1];
  const void* Wc = d_in[wi + 2];
  const void* bc = d_in[wi + 3];

  short* ws  = (short*)d_ws;
  short* qp  = ws;                 // [b,h,t,d] bf16
  short* kp  = ws + SZE;           // [b,h,t,d] bf16
  short* vpt = ws + 2 * SZE;       // [b,h,d,t] bf16
  short* y   = ws + 3 * SZE;       // [b,t,c]   bf16

  short* ext = ws + 4 * SZE;
  const size_t needed = (4 * SZE + CVT_TOT) * sizeof(short);  // ~33.6 MB
  const bool pre = (ws_size >= needed);

  dim3 blk(256);
  if (pre) {
    cvt_k<<<dim3((unsigned)((CVT_TOT + 1023) / 1024)), blk, 0, stream>>>(
        q, k, v, Wk, Wc, bk, bc, ext);
    const short* gq  = ext;
    const short* gk  = ext + QN;
    const short* gv  = ext + 2 * QN;
    const short* gwk = ext + 3 * QN;
    const short* gwc = ext + 3 * QN + WN;
    const short* gbk = ext + 3 * QN + 2 * WN;
    const short* gbc = ext + 3 * QN + 2 * WN + BN;

    gemm_qkv_a<<<dim3(768), blk, 0, stream>>>(gq, gk, gv, gwk, gbk, qp);
    attn_k4<<<dim3(32, 16), blk, 0, stream>>>(qp, kp, vpt, y);
    gemm_out_a<<<dim3(512), blk, 0, stream>>>(y, gwc, gbc, (float*)d_out);
  } else {
    gemm2_k<1><<<dim3(96, 16), blk, 0, stream>>>(q, k, v, Wk, bk, qp);
    attn_k4<<<dim3(32, 16), blk, 0, stream>>>(qp, kp, vpt, y);
    gemm2_k<0><<<dim3(32, 16), blk, 0, stream>>>(y, nullptr, nullptr, Wc, bc, d_out);
  }
}

// Round 10
// 156.263 us; speedup vs baseline: 1.0309x; 1.0024x over previous
//
#include <hip/hip_runtime.h>

// Problem constants: B=2, T=1024, C=1024, H=16, D=64, K=C=1024.
#define T_DIM 1024
#define C_DIM 1024
#define H_DIM 16
#define D_DIM 64
#define KD    1024

typedef short  short8  __attribute__((ext_vector_type(8)));
typedef short  short4v __attribute__((ext_vector_type(4)));
typedef float  f32x4   __attribute__((ext_vector_type(4)));

__device__ __forceinline__ float bf2f(short s) {
  return __uint_as_float(((unsigned)(unsigned short)s) << 16);
}
__device__ __forceinline__ short f2bf(float f) {
  unsigned u = __float_as_uint(f);
  u += 0x7fffu + ((u >> 16) & 1u);   // round-to-nearest-even
  return (short)(u >> 16);
}
__device__ __forceinline__ unsigned pk2(float lo, float hi) {
  return ((unsigned)(unsigned short)f2bf(lo)) | (((unsigned)(unsigned short)f2bf(hi)) << 16);
}

// Async global->LDS 16B (m97 pattern; validated R12). Dest = uniform base + lane*16.
__device__ __forceinline__ void gl2lds16(const short* g, short* l) {
  __builtin_amdgcn_global_load_lds(
      (const __attribute__((address_space(1))) unsigned int*)(const void*)g,
      (__attribute__((address_space(3))) unsigned int*)(void*)l,
      16, 0, 0);
}

// Legacy-path helpers (fallback only).
__device__ __forceinline__ short8 ldfrag(const void* p, size_t off, int isf32) {
  if (isf32) {
    const float* q = (const float*)p + off;
    f32x4 lo = *(const f32x4*)q;
    f32x4 hi = *(const f32x4*)(q + 4);
    short8 r;
#pragma unroll
    for (int j = 0; j < 4; ++j) { r[j] = f2bf(lo[j]); r[j + 4] = f2bf(hi[j]); }
    return r;
  }
  return *(const short8*)((const short*)p + off);
}
__device__ __forceinline__ float ldbias(const void* b, int i, int isf32) {
  return isf32 ? ((const float*)b)[i] : bf2f(((const short*)b)[i]);
}

// In-kernel dtype probe (validated R6-R12).
__device__ __forceinline__ int detect_f32_inblock(const unsigned* w, int lane) {
  int c = 0;
#pragma unroll
  for (int i = 0; i < 4; ++i) {
    unsigned e = (w[lane * 4 + i] >> 7) & 0xffu;
    c += (e >= 110u && e <= 135u) ? 1 : 0;
  }
#pragma unroll
  for (int off = 32; off; off >>= 1) c += __shfl_xor(c, off);
  return (c < 128) ? 1 : 0;
}

#define SZE  ((size_t)2 * T_DIM * C_DIM)   // 2,097,152 elements
#define QN   ((size_t)2097152)
#define WN   ((size_t)1048576)
#define BN   ((size_t)1024)
#define CVT_TOT (3 * QN + 2 * WN + 2 * BN) // 8,390,656 (divisible by 4)

// ---------------------------------------------------------------------------
// One-time bf16 conversion prepass (validated R9-R12).
// ---------------------------------------------------------------------------
__global__ __launch_bounds__(256) void cvt_k(const void* __restrict__ q,
                                             const void* __restrict__ k,
                                             const void* __restrict__ v,
                                             const void* __restrict__ wk,
                                             const void* __restrict__ wc,
                                             const void* __restrict__ bk,
                                             const void* __restrict__ bc,
                                             short* __restrict__ dst)
{
  const int lane = threadIdx.x & 63;
  const int f = detect_f32_inblock((const unsigned*)q, lane);

  const size_t idx = (size_t)blockIdx.x * 1024 + threadIdx.x * 4;
  if (idx >= CVT_TOT) return;
  const void* src;
  size_t loc;
  if      (idx <     QN)          { src = q;  loc = idx; }
  else if (idx < 2 * QN)          { src = k;  loc = idx - QN; }
  else if (idx < 3 * QN)          { src = v;  loc = idx - 2 * QN; }
  else if (idx < 3 * QN + WN)     { src = wk; loc = idx - 3 * QN; }
  else if (idx < 3 * QN + 2 * WN) { src = wc; loc = idx - 3 * QN - WN; }
  else if (idx < 3 * QN + 2 * WN + BN) { src = bk; loc = idx - 3 * QN - 2 * WN; }
  else                            { src = bc; loc = idx - 3 * QN - 2 * WN - BN; }

  short4v o;
  if (f) {
    f32x4 x = *(const f32x4*)((const float*)src + loc);
#pragma unroll
    for (int j = 0; j < 4; ++j) o[j] = f2bf(x[j]);
  } else {
    o = *(const short4v*)((const short*)src + loc);
  }
  *(short4v*)(dst + idx) = o;
}

// ---------------------------------------------------------------------------
// BK=64 XOR-swizzled async staging (R13-verified scheme, unchanged).
// ---------------------------------------------------------------------------
__device__ __forceinline__ void stage8x8(const short* gsrc, short* S, int R0,
                                         int lane, int koff) {
  const int rw = R0 + (lane >> 3);
  const int q  = (lane & 7) ^ (rw & 7);
  gl2lds16(gsrc + (size_t)rw * KD + koff + q * 8, &S[R0 * 64]);
}
__device__ __forceinline__ short8 fragread64(const short* S, int row, int chunk) {
  const int sl = (row << 3) + (chunk ^ (row & 7));
  return *(const short8*)&S[sl << 3];
}

// ---------------------------------------------------------------------------
// Async fused QKV GEMM (R17 config, frozen): 128x64, BK=64, dbuf, XCD remap.
// ---------------------------------------------------------------------------
__global__ __launch_bounds__(256) void gemm_qkv_a(const short* __restrict__ X0,
                                                  const short* __restrict__ X1,
                                                  const short* __restrict__ X2,
                                                  const short* __restrict__ Wv,
                                                  const short* __restrict__ Bv,
                                                  short* __restrict__ outv)
{
  const int tid  = threadIdx.x;
  const int lane = tid & 63;
  const int wave = tid >> 6;
  const int col16 = lane & 15;
  const int quad  = lane >> 4;

  // XCD-L2 ownership remap (bijective: 768 = 8 XCD x 6 m x 16 c)
  const int f   = blockIdx.x;
  const int xcd = f & 7;
  const int j   = f >> 3;                 // [0,96)
  const int mt  = xcd * 6 + (j % 6);      // [0,48)
  const int ct  = j / 6;                  // [0,16)
  const int m0 = mt * 128;
  const int c0 = ct * 64;

  const int src = m0 >> 11;               // 0=q 1=k 2=v
  const short* Xv = (src == 0) ? X0 : (src == 1) ? X1 : X2;
  const int arow = m0 & 2047;
  const bool isv = (src == 2);
  short* outb = outv + (size_t)src * SZE;

  __shared__ short As[2][128 * 64];       // 32 KB (double-buffered)
  __shared__ short Bs[2][64 * 64];        // 16 KB (double-buffered)

  const short* Xg = Xv + (size_t)arow * KD;
  const short* Wg = Wv + (size_t)c0 * KD;

  f32x4 acc[2][4] = {};                   // [i = m-sub (wave*32+i*16)][j = c-sub]

  // prologue: fill buffer 0
  stage8x8(Xg, As[0], wave * 32,      lane, 0);
  stage8x8(Xg, As[0], wave * 32 + 8,  lane, 0);
  stage8x8(Xg, As[0], wave * 32 + 16, lane, 0);
  stage8x8(Xg, As[0], wave * 32 + 24, lane, 0);
  stage8x8(Wg, Bs[0], wave * 16,      lane, 0);
  stage8x8(Wg, Bs[0], wave * 16 + 8,  lane, 0);
  __syncthreads();                        // drains vmcnt; buf0 ready

  int cur = 0;
  for (int k0 = 0; k0 < KD; k0 += 64) {
    // prefetch next K-tile into the other buffer (overlaps compute below)
    if (k0 + 64 < KD) {
      short* An = As[cur ^ 1];
      short* Bn = Bs[cur ^ 1];
      stage8x8(Xg, An, wave * 32,      lane, k0 + 64);
      stage8x8(Xg, An, wave * 32 + 8,  lane, k0 + 64);
      stage8x8(Xg, An, wave * 32 + 16, lane, k0 + 64);
      stage8x8(Xg, An, wave * 32 + 24, lane, k0 + 64);
      stage8x8(Wg, Bn, wave * 16,      lane, k0 + 64);
      stage8x8(Wg, Bn, wave * 16 + 8,  lane, k0 + 64);
    }

    const short* Ac = As[cur];
    const short* Bc = Bs[cur];
#pragma unroll
    for (int kk = 0; kk < 2; ++kk) {
      short8 fx[2], fw[4];
#pragma unroll
      for (int i = 0; i < 2; ++i)
        fx[i] = fragread64(Ac, wave * 32 + i * 16 + col16, kk * 4 + quad);
#pragma unroll
      for (int jj = 0; jj < 4; ++jj)
        fw[jj] = fragread64(Bc, jj * 16 + col16, kk * 4 + quad);

      if (isv) {
#pragma unroll
        for (int i = 0; i < 2; ++i)
#pragma unroll
          for (int jj = 0; jj < 4; ++jj)
            acc[i][jj] = __builtin_amdgcn_mfma_f32_16x16x32_bf16(fx[i], fw[jj], acc[i][jj], 0, 0, 0);
      } else {
#pragma unroll
        for (int i = 0; i < 2; ++i)
#pragma unroll
          for (int jj = 0; jj < 4; ++jj)
            acc[i][jj] = __builtin_amdgcn_mfma_f32_16x16x32_bf16(fw[jj], fx[i], acc[i][jj], 0, 0, 0);
      }
    }

    __syncthreads();   // vmcnt(0): prefetch landed; lgkm: reads done; all waves synced
    cur ^= 1;
  }

  if (isv) {
    // NORM: col=c(d), rows=m(t) -> vpt [b,h,d,t]   (verified R5+)
#pragma unroll
    for (int i = 0; i < 2; ++i) {
#pragma unroll
      for (int jj = 0; jj < 4; ++jj) {
        const int c  = c0 + jj * 16 + col16;
        const int t0 = arow + wave * 32 + i * 16 + quad * 4;
        const float bv = bf2f(Bv[c]);
        short4v pk;
#pragma unroll
        for (int r = 0; r < 4; ++r) pk[r] = f2bf(acc[i][jj][r] + bv);
        const int bb = t0 >> 10, t = t0 & 1023, h = c >> 6, d = c & 63;
        size_t off = (size_t)((bb * H_DIM + h) * D_DIM + d) * T_DIM + t;
        *(short4v*)(outb + off) = pk;
      }
    }
  } else {
    // TRANS: col=m, rows=c -> qp/kp [b,h,t,d]   (verified R5+)
#pragma unroll
    for (int i = 0; i < 2; ++i) {
#pragma unroll
      for (int jj = 0; jj < 4; ++jj) {
        const int m  = arow + wave * 32 + i * 16 + col16;
        const int cb = c0 + jj * 16 + quad * 4;
        short4v bv4 = *(const short4v*)(Bv + cb);
        short4v pk;
#pragma unroll
        for (int r = 0; r < 4; ++r) pk[r] = f2bf(acc[i][jj][r] + bf2f(bv4[r]));
        const int bb = m >> 10, t = m & 1023, h = cb >> 6, d = cb & 63;
        size_t off = ((size_t)(bb * H_DIM + h) << 16) + (size_t)t * D_DIM + d;
        *(short4v*)(outb + off) = pk;
      }
    }
  }
}

// ---------------------------------------------------------------------------
// Async final GEMM (R17 config, frozen): 64x64, BK=64, dbuf, XCD remap.
// ---------------------------------------------------------------------------
__global__ __launch_bounds__(256) void gemm_out_a(const short* __restrict__ Xb,
                                                  const short* __restrict__ Wv,
                                                  const short* __restrict__ Bv,
                                                  float* __restrict__ outv)
{
  const int tid  = threadIdx.x;
  const int lane = tid & 63;
  const int wave = tid >> 6;
  const int col16 = lane & 15;
  const int quad  = lane >> 4;
  const int wm = wave & 1;
  const int wn = wave >> 1;

  // XCD-L2 ownership remap (bijective: 512 = 8 XCD x 4 m x 16 c)
  const int f   = blockIdx.x;
  const int xcd = f & 7;
  const int j   = f >> 3;                 // [0,64)
  const int mt  = xcd * 4 + (j % 4);      // [0,32)
  const int ct  = j / 4;                  // [0,16)
  const int m0 = mt * 64;
  const int c0 = ct * 64;

  __shared__ short As[2][64 * 64];        // 16 KB
  __shared__ short Bs[2][64 * 64];        // 16 KB

  const short* Xg = Xb + (size_t)m0 * KD;
  const short* Wg = Wv + (size_t)c0 * KD;

  f32x4 acc[2][2] = {};

  stage8x8(Xg, As[0], wave * 16,     lane, 0);
  stage8x8(Xg, As[0], wave * 16 + 8, lane, 0);
  stage8x8(Wg, Bs[0], wave * 16,     lane, 0);
  stage8x8(Wg, Bs[0], wave * 16 + 8, lane, 0);
  __syncthreads();

  int cur = 0;
  for (int k0 = 0; k0 < KD; k0 += 64) {
    if (k0 + 64 < KD) {
      short* An = As[cur ^ 1];
      short* Bn = Bs[cur ^ 1];
      stage8x8(Xg, An, wave * 16,     lane, k0 + 64);
      stage8x8(Xg, An, wave * 16 + 8, lane, k0 + 64);
      stage8x8(Wg, Bn, wave * 16,     lane, k0 + 64);
      stage8x8(Wg, Bn, wave * 16 + 8, lane, k0 + 64);
    }

    const short* Ac = As[cur];
    const short* Bc = Bs[cur];
#pragma unroll
    for (int kk = 0; kk < 2; ++kk) {
      short8 fx[2], fw[2];
#pragma unroll
      for (int i = 0; i < 2; ++i)
        fx[i] = fragread64(Ac, wm * 32 + i * 16 + col16, kk * 4 + quad);
#pragma unroll
      for (int jj = 0; jj < 2; ++jj)
        fw[jj] = fragread64(Bc, wn * 32 + jj * 16 + col16, kk * 4 + quad);

#pragma unroll
      for (int i = 0; i < 2; ++i)
#pragma unroll
        for (int jj = 0; jj < 2; ++jj)
          acc[i][jj] = __builtin_amdgcn_mfma_f32_16x16x32_bf16(fw[jj], fx[i], acc[i][jj], 0, 0, 0);
    }

    __syncthreads();
    cur ^= 1;
  }

#pragma unroll
  for (int i = 0; i < 2; ++i) {
#pragma unroll
    for (int jj = 0; jj < 2; ++jj) {
      const int m  = m0 + wm * 32 + i * 16 + col16;
      const int cb = c0 + wn * 32 + jj * 16 + quad * 4;
      f32x4 pv;
#pragma unroll
      for (int r = 0; r < 4; ++r) pv[r] = acc[i][jj][r] + bf2f(Bv[cb + r]);
      *(f32x4*)(outv + (size_t)m * C_DIM + cb) = pv;
    }
  }
}

// ---------------------------------------------------------------------------
// Legacy LDS-staged GEMM (R6/R10-verified) — fallback when ws too small.
// ---------------------------------------------------------------------------
#define LDSP 40

template<int KIND>
__global__ __launch_bounds__(256) void gemm2_k(const void* __restrict__ X0,
                                               const void* __restrict__ X1,
                                               const void* __restrict__ X2,
                                               const void* __restrict__ Wv,
                                               const void* __restrict__ Bv,
                                               void* __restrict__ outv)
{
  const int tid  = threadIdx.x;
  const int lane = tid & 63;
  const int wave = tid >> 6;
  const int col16 = lane & 15;
  const int quad  = lane >> 4;
  const int wm = wave & 1;
  const int wn = wave >> 1;

  const int f  = detect_f32_inblock((const unsigned*)Wv, lane);
  const int wf = f;
  const int xf = (KIND == 1) ? f : 0;

  const int m0 = blockIdx.x * 64;
  const int c0 = blockIdx.y * 64;

  const void* Xv = X0;
  int arow = m0;
  bool isv = false;
  short* outb = (short*)outv;
  if (KIND == 1) {
    const int src = m0 >> 11;
    Xv = (src == 0) ? X0 : (src == 1) ? X1 : X2;
    arow = m0 & 2047;
    isv = (src == 2);
    outb = (short*)outv + (size_t)src * SZE;
  }

  __shared__ short As[64 * LDSP];
  __shared__ short Bs[64 * LDSP];

  const int srow = tid >> 2;
  const int sc8  = tid & 3;

  f32x4 acc[2][2] = {};

  for (int k0 = 0; k0 < KD; k0 += 32) {
    short8 va = ldfrag(Xv, (size_t)(arow + srow) * KD + k0 + sc8 * 8, xf);
    short8 vb = ldfrag(Wv, (size_t)(c0 + srow) * KD + k0 + sc8 * 8, wf);
    if (k0) __syncthreads();
    *(short8*)&As[srow * LDSP + sc8 * 8] = va;
    *(short8*)&Bs[srow * LDSP + sc8 * 8] = vb;
    __syncthreads();

    short8 fx[2], fw[2];
#pragma unroll
    for (int i = 0; i < 2; ++i)
      fx[i] = *(const short8*)&As[(wm * 32 + i * 16 + col16) * LDSP + quad * 8];
#pragma unroll
    for (int jj = 0; jj < 2; ++jj)
      fw[jj] = *(const short8*)&Bs[(wn * 32 + jj * 16 + col16) * LDSP + quad * 8];

    if (KIND == 1 && isv) {
#pragma unroll
      for (int i = 0; i < 2; ++i)
#pragma unroll
        for (int jj = 0; jj < 2; ++jj)
          acc[i][jj] = __builtin_amdgcn_mfma_f32_16x16x32_bf16(fx[i], fw[jj], acc[i][jj], 0, 0, 0);
    } else {
#pragma unroll
      for (int i = 0; i < 2; ++i)
#pragma unroll
        for (int jj = 0; jj < 2; ++jj)
          acc[i][jj] = __builtin_amdgcn_mfma_f32_16x16x32_bf16(fw[jj], fx[i], acc[i][jj], 0, 0, 0);
    }
  }

  if (KIND == 1 && isv) {
#pragma unroll
    for (int i = 0; i < 2; ++i) {
#pragma unroll
      for (int jj = 0; jj < 2; ++jj) {
        const int c  = c0 + wn * 32 + jj * 16 + col16;
        const int t0 = arow + wm * 32 + i * 16 + quad * 4;
        const float bv = ldbias(Bv, c, wf);
        short4v pk;
#pragma unroll
        for (int r = 0; r < 4; ++r) pk[r] = f2bf(acc[i][jj][r] + bv);
        const int bb = t0 >> 10, t = t0 & 1023, h = c >> 6, d = c & 63;
        size_t off = (size_t)((bb * H_DIM + h) * D_DIM + d) * T_DIM + t;
        *(short4v*)(outb + off) = pk;
      }
    }
  } else {
#pragma unroll
    for (int i = 0; i < 2; ++i) {
#pragma unroll
      for (int jj = 0; jj < 2; ++jj) {
        const int m  = arow + wm * 32 + i * 16 + col16;
        const int cb = c0 + wn * 32 + jj * 16 + quad * 4;
        if (KIND == 0) {
          f32x4 pv;
#pragma unroll
          for (int r = 0; r < 4; ++r) pv[r] = acc[i][jj][r] + ldbias(Bv, cb + r, wf);
          *(f32x4*)((float*)outv + (size_t)m * C_DIM + cb) = pv;
        } else {
          short4v pk;
#pragma unroll
          for (int r = 0; r < 4; ++r) pk[r] = f2bf(acc[i][jj][r] + ldbias(Bv, cb + r, wf));
          const int bb = m >> 10, t = m & 1023, h = cb >> 6, d = cb & 63;
          size_t off = ((size_t)(bb * H_DIM + h) << 16) + (size_t)t * D_DIM + d;
          *(short4v*)(outb + off) = pk;
        }
      }
    }
  }
}

// ---------------------------------------------------------------------------
// Causal attention (R22 = R21 + register budget fix).
//  R19 profile showed attn VGPR_Count=44 vs a live set >60 (bQ 8 + O 16 +
//  st 8 + aV 16 + addressing): the allocator, targeting max occupancy,
//  SPILLED the accumulators to scratch — explaining the 7-10x gap between
//  the ~4-6us chain model and the measured ~39us, and why R20's register
//  pipeline (more liveness -> more spill) nulled.
//  Fix: __launch_bounds__(256, 2) — only 2048 waves exist (= 2/SIMD), so
//  grant up to 256 VGPR/wave; occupancy demand unchanged, spills gone.
//  Structure identical to R21: one wave owns one q-tile, zero LDS/barriers.
// ---------------------------------------------------------------------------
__global__ __launch_bounds__(256, 2) void attn_k4(const short* __restrict__ qp,
                                                  const short* __restrict__ kp,
                                                  const short* __restrict__ vpt,
                                                  short* __restrict__ y)
{
  const int lane = threadIdx.x & 63;
  const int wave = threadIdx.x >> 6;
  const int col  = lane & 15;
  const int quad = lane >> 4;
  const int bh = blockIdx.x;                 // XCD = bh % 8 (heuristic)
  const int b = bh >> 4, h = bh & 15;
  const int g = (int)blockIdx.y;             // [0,16)
  const int qt = (wave == 0) ? 2 * g
               : (wave == 1) ? 63 - 2 * g
               : (wave == 2) ? 2 * g + 1
               :               62 - 2 * g;
  const int q0 = qt * 16;
  const int myq = q0 + col;

  const short* qph = qp  + (size_t)bh * (T_DIM * D_DIM);
  const short* kph = kp  + (size_t)bh * (T_DIM * D_DIM);
  const short* vph = vpt + (size_t)bh * (D_DIM * T_DIM);

  const int cnt = (q0 + 47) >> 5;            // key tiles [0, cnt), cnt >= 1

  short8 bQ[2];
#pragma unroll
  for (int kk = 0; kk < 2; ++kk)
    bQ[kk] = *(const short8*)(qph + (size_t)(q0 + col) * D_DIM + kk * 32 + quad * 8);

  f32x4 O[4] = {};
  float rs = 0.0f;

  const int slA = col + ((quad & 1) * 32);
  const int slB = slA + 16;

  // K(jt=0) software pipeline: preload tile 0.
  short8 cK0a, cK0b;
  {
    const short* p0 = kph + (size_t)(col) * D_DIM + quad * 8;
    cK0a = *(const short8*)(p0);
    cK0b = *(const short8*)(p0 + 32);
  }

#pragma unroll 1
  for (int kt = 0; kt < cnt; ++kt) {
    const int kb = kt * 32;

    // --- issue all independent loads first ---
    const short* kb1 = kph + (size_t)(kb + 16 + col) * D_DIM + quad * 8;
    short8 aK1a = *(const short8*)(kb1);
    short8 aK1b = *(const short8*)(kb1 + 32);
    // next-tile K(jt=0) (last iteration over-reads into vpt region: safe)
    const short* nb0 = kph + (size_t)(kb + 32 + col) * D_DIM + quad * 8;
    short8 nK0a = *(const short8*)(nb0);
    short8 nK0b = *(const short8*)(nb0 + 32);

    // --- QK^T (jt=0 operands resident from previous iteration) ---
    f32x4 st[2];
    {
      f32x4 s = {0.f, 0.f, 0.f, 0.f};
      __builtin_amdgcn_s_setprio(1);
      s = __builtin_amdgcn_mfma_f32_16x16x32_bf16(cK0a, bQ[0], s, 0, 0, 0);
      s = __builtin_amdgcn_mfma_f32_16x16x32_bf16(cK0b, bQ[1], s, 0, 0, 0);
      st[0] = s;
      f32x4 t = {0.f, 0.f, 0.f, 0.f};
      t = __builtin_amdgcn_mfma_f32_16x16x32_bf16(aK1a, bQ[0], t, 0, 0, 0);
      t = __builtin_amdgcn_mfma_f32_16x16x32_bf16(aK1b, bQ[1], t, 0, 0, 0);
      __builtin_amdgcn_s_setprio(0);
      st[1] = t;
    }

    // --- softmax (no-max, causal mask) ---
#pragma unroll
    for (int jt = 0; jt < 2; ++jt) {
#pragma unroll
      for (int r = 0; r < 4; ++r) {
        const int key = kb + jt * 16 + quad * 4 + r;
        float p = __expf(st[jt][r] * 0.125f);
        p = (key > myq) ? 0.0f : p;
        st[jt][r] = p;
        rs += p;
      }
    }

    // V loads before the shuffle phase (bpermute latency covers them).
    short8 aV[4];
#pragma unroll
    for (int dt = 0; dt < 4; ++dt)
      aV[dt] = *(const short8*)(vph + (size_t)(dt * 16 + col) * T_DIM + kb + quad * 8);

    // --- P redistribution (verified R11/R12 shuffle scheme) ---
    const int a0 = (int)pk2(st[0][0], st[0][1]);
    const int a1 = (int)pk2(st[0][2], st[0][3]);
    const int b0 = (int)pk2(st[1][0], st[1][1]);
    const int b1 = (int)pk2(st[1][2], st[1][3]);
    const int tA0 = __shfl(a0, slA, 64), tB0 = __shfl(b0, slA, 64);
    const int tA1 = __shfl(a1, slA, 64), tB1 = __shfl(b1, slA, 64);
    const int tA2 = __shfl(a0, slB, 64), tB2 = __shfl(b0, slB, 64);
    const int tA3 = __shfl(a1, slB, 64), tB3 = __shfl(b1, slB, 64);
    union { unsigned u[4]; short8 s8; } uu;
    uu.u[0] = (unsigned)((quad < 2) ? tA0 : tB0);
    uu.u[1] = (unsigned)((quad < 2) ? tA1 : tB1);
    uu.u[2] = (unsigned)((quad < 2) ? tA2 : tB2);
    uu.u[3] = (unsigned)((quad < 2) ? tA3 : tB3);
    const short8 bP32 = uu.s8;

    // --- PV ---
    __builtin_amdgcn_s_setprio(1);
#pragma unroll
    for (int dt = 0; dt < 4; ++dt)
      O[dt] = __builtin_amdgcn_mfma_f32_16x16x32_bf16(aV[dt], bP32, O[dt], 0, 0, 0);
    __builtin_amdgcn_s_setprio(0);

    // rotate the K(jt=0) pipeline
    cK0a = nK0a;
    cK0b = nK0b;
  }

  // Complete softmax denominator: reduce across the 4 quads (wave owns all
  // keys of its q-tile, so this is the full sum).
  rs += __shfl_xor(rs, 16);
  rs += __shfl_xor(rs, 32);
  const float rl = 1.0f / rs;

  // Direct output write: lane(col,quad) holds d = dt*16 + quad*4 + r for
  // q-row t = q0 + col (verified C-layout, R5+).
  const int t = q0 + col;
  const size_t ybase = ((size_t)(b * T_DIM + t)) * C_DIM + h * D_DIM + quad * 4;
#pragma unroll
  for (int dt = 0; dt < 4; ++dt) {
    short4v pk;
#pragma unroll
    for (int r = 0; r < 4; ++r) pk[r] = f2bf(O[dt][r] * rl);
    *(short4v*)(y + ybase + dt * 16) = pk;
  }
}

// ---------------------------------------------------------------------------
extern "C" void kernel_launch(void* const* d_in, const int* in_sizes, int n_in,
                              void* d_out, int out_size, void* d_ws, size_t ws_size,
                              hipStream_t stream) {
  const void* q = d_in[0];
  const void* k = d_in[1];
  const void* v = d_in[2];
  int wi = (n_in >= 8 && in_sizes[4] == C_DIM * C_DIM) ? 4 : 3;
  const void* Wk = d_in[wi];
  const void* bk = d_in[wi + 1];
  const void* Wc = d_in[wi + 2];
  const void* bc = d_in[wi + 3];

  short* ws  = (short*)d_ws;
  short* qp  = ws;                 // [b,h,t,d] bf16
  short* kp  = ws + SZE;           // [b,h,t,d] bf16
  short* vpt = ws + 2 * SZE;       // [b,h,d,t] bf16
  short* y   = ws + 3 * SZE;       // [b,t,c]   bf16

  short* ext = ws + 4 * SZE;
  const size_t needed = (4 * SZE + CVT_TOT) * sizeof(short);  // ~33.6 MB
  const bool pre = (ws_size >= needed);

  dim3 blk(256);
  if (pre) {
    cvt_k<<<dim3((unsigned)((CVT_TOT + 1023) / 1024)), blk, 0, stream>>>(
        q, k, v, Wk, Wc, bk, bc, ext);
    const short* gq  = ext;
    const short* gk  = ext + QN;
    const short* gv  = ext + 2 * QN;
    const short* gwk = ext + 3 * QN;
    const short* gwc = ext + 3 * QN + WN;
    const short* gbk = ext + 3 * QN + 2 * WN;
    const short* gbc = ext + 3 * QN + 2 * WN + BN;

    gemm_qkv_a<<<dim3(768), blk, 0, stream>>>(gq, gk, gv, gwk, gbk, qp);
    attn_k4<<<dim3(32, 16), blk, 0, stream>>>(qp, kp, vpt, y);
    gemm_out_a<<<dim3(512), blk, 0, stream>>>(y, gwc, gbc, (float*)d_out);
  } else {
    gemm2_k<1><<<dim3(96, 16), blk, 0, stream>>>(q, k, v, Wk, bk, qp);
    attn_k4<<<dim3(32, 16), blk, 0, stream>>>(qp, kp, vpt, y);
    gemm2_k<0><<<dim3(32, 16), blk, 0, stream>>>(y, nullptr, nullptr, Wc, bc, d_out);
  }
}